// Round 4
// baseline (64.970 us; speedup 1.0000x reference)
//
#include <hip/hip_runtime.h>
#include <hip/hip_bf16.h>
#include <math.h>

#define NB 2
#define NT 256
#define NN 512
#define NH 64
#define NS 8
#define NC 8

// workspace layout (float offsets)
#define OFF_H      0                          // 2*512*64 = 65536
#define OFF_PVEC   65536                      // 65536   (pre_i + be1)
#define OFF_INVN   (2*65536)                  // 1024
#define OFF_HJBF   (2*65536 + 1024)           // 65536 shorts = 32768 floats
#define OFF_BFRAG  (2*65536 + 1024 + 32768)   // 12288 shorts = 6144 floats
#define OFF_UNSYM  (OFF_BFRAG + 6144)         // 2*512*512 = 524288
// total = 695296 floats ~= 2.78 MB

typedef __attribute__((ext_vector_type(8))) short short8;
typedef __attribute__((ext_vector_type(4))) float f32x4;
typedef __attribute__((ext_vector_type(4))) unsigned uint4v;

__device__ __forceinline__ float softplusf(float x){
  if (x > 20.f) return x;
  return log1pf(expf(x));
}

__device__ __forceinline__ short f2bf(float x){
  __hip_bfloat16 h = __float2bfloat16(x);
  return __builtin_bit_cast(short, h);
}

__device__ __forceinline__ unsigned pk2(float a, float b){
  unsigned lo = (unsigned short)f2bf(a);
  unsigned hi = (unsigned short)f2bf(b);
  return lo | (hi << 16);
}

// ---------------- Kernel FRONT: stats + node MLP (blocks 0..63), bfrag prep (64..111)
// stats+node block: b = blk>>5, node chunk nc = blk&31 (16 nodes).
// Phase 1: temporal stats into s_dyn. Phase 2: 4 rounds x 4 waves, wave = one node,
// lane = channel (identical math to the old k_node).
__global__ __launch_bounds__(256) void k_front(
    const float* __restrict__ x, const float* __restrict__ mask,
    const float* __restrict__ sctx,
    const float* __restrict__ W1, const float* __restrict__ b1,
    const float* __restrict__ W2, const float* __restrict__ b2,
    const float* __restrict__ We1, const float* __restrict__ be1,
    float* __restrict__ hg, float* __restrict__ pvec,
    float* __restrict__ invn, short* __restrict__ hjbf,
    short* __restrict__ bfrag){
  int blk = blockIdx.x;
  int tid = threadIdx.x;

  if (blk >= 64){
    // ---- bfrag prep: B[k][n] -> MFMA B-fragments, bf16 ----
    // k<64: Wa = We1 rows 128..191 ; k<128: Wp = rows 192..255 ; k<192: Wj = rows 64..127
    int idx = (blk - 64)*256 + tid;          // 0..12287
    if (idx < 12288){
      int e    = idx & 7;
      int lane = (idx >> 3) & 63;
      int frag = idx >> 9;                   // ks*4+nt
      int nt = frag & 3, ks = frag >> 2;
      int k = ks*32 + (lane >> 4)*8 + e;
      int n = nt*16 + (lane & 15);
      int row = (k < 64) ? (128 + k) : (k < 128) ? (192 + (k - 64)) : (64 + (k - 128));
      bfrag[idx] = f2bf(We1[row*NH + n]);
    }
    return;
  }

  int b  = blk >> 5;
  int n0 = (blk & 31) * 16;

  // ---- phase 1: stats (16 nl x 16 t-slices) ----
  int nl = tid & 15;
  int ts = tid >> 4;
  int n  = n0 + nl;

  float cnt = 0.f, sx = 0.f, sxx = 0.f;
  int lastt = 0;
  for (int t = ts*16; t < ts*16 + 16; ++t){
    int idx = (b*NT + t)*NN + n;
    float xv = x[idx];
    float mv = mask[idx];
    bool obs = (mv < 0.5f);
    if (obs){ cnt += 1.f; sx += xv; sxx += xv*xv; lastt = t; }
  }
  __shared__ float s_cnt[16][16], s_sx[16][16], s_sxx[16][16];
  __shared__ int   s_lt[16][16];
  __shared__ float s_dyn[16][4];
  s_cnt[ts][nl] = cnt; s_sx[ts][nl] = sx; s_sxx[ts][nl] = sxx; s_lt[ts][nl] = lastt;
  __syncthreads();
  if (ts == 0){
    for (int s2 = 1; s2 < 16; ++s2){
      cnt += s_cnt[s2][nl]; sx += s_sx[s2][nl]; sxx += s_sxx[s2][nl];
      lastt = max(lastt, s_lt[s2][nl]);
    }
    float cc   = fmaxf(cnt, 1.f);
    float mean = sx / cc;
    float var  = sxx / cc - mean*mean;
    float stdv = sqrtf(fmaxf(var, 0.f) + 1e-6f);
    float last = x[(b*NT + lastt)*NN + n];
    float mr   = 1.f - cnt * (1.f/(float)NT);
    s_dyn[nl][0] = mean; s_dyn[nl][1] = stdv; s_dyn[nl][2] = last; s_dyn[nl][3] = mr;
  }
  __syncthreads();

  // ---- phase 2: node MLP, 4 rounds x 4 waves ----
  int w = tid >> 6, c = tid & 63;
  __shared__ float s_f[4][12];
  __shared__ float s_h1[4][64];
  __shared__ float s_h2[4][64];

  for (int r = 0; r < 4; ++r){
    int nloc = r*4 + w;                 // node local 0..15
    int gn   = n0 + nloc;
    int bn   = b*NN + gn;
    if (c < 4)       s_f[w][c] = s_dyn[nloc][c];
    else if (c < 12) s_f[w][c] = sctx[gn*NS + (c-4)];
    __syncthreads();

    float a = b1[c];
    #pragma unroll
    for (int k = 0; k < 12; ++k) a = fmaf(s_f[w][k], W1[k*NH + c], a);
    s_h1[w][c] = fmaxf(a, 0.f);
    __syncthreads();

    float a2 = b2[c];
    #pragma unroll 8
    for (int k = 0; k < 64; ++k) a2 = fmaf(s_h1[w][k], W2[k*NH + c], a2);
    a2 = fmaxf(a2, 0.f);

    float sq = a2*a2;
    #pragma unroll
    for (int m = 1; m < 64; m <<= 1) sq += __shfl_xor(sq, m);
    float inv = 1.f / fmaxf(sqrtf(sq), 1e-12f);

    s_h2[w][c] = a2;
    __syncthreads();

    float pi = be1[c];
    #pragma unroll 8
    for (int k = 0; k < 64; ++k) pi = fmaf(s_h2[w][k], We1[k*NH + c], pi);  // Wi rows 0..63

    hg  [bn*64 + c] = a2;
    pvec[bn*64 + c] = pi;
    hjbf[bn*64 + c] = f2bf(a2);
    if (c == 0) invn[bn] = inv;
  }
}

// ---------------- Kernel C: MFMA pairwise edge MLP + logits + row softmax -----
// grid NB*NN (block per (b,i)), 256 thr = 4 waves; wave handles 16-j tiles
// it = w, w+4, ..., 28. MFMA 16x16x32 bf16: M=16 j, N=64 ch (4 n-tiles),
// K=192 ([|hi-hj|, hi*hj, hj]) = 6 k-steps. Prior computed inline from coords.
__global__ __launch_bounds__(256) void k_pair(
    const float* __restrict__ hg, const float* __restrict__ pvec,
    const float* __restrict__ invn, const short* __restrict__ hjbf,
    const short* __restrict__ bfrag, const float* __restrict__ coords,
    const float* __restrict__ We2, const float* __restrict__ be2,
    const float* __restrict__ s_sl, const float* __restrict__ s_ps,
    const float* __restrict__ s_ss, const float* __restrict__ s_tp,
    float* __restrict__ unsym){
  int blk = blockIdx.x;
  int b = blk >> 9, i = blk & (NN-1);
  int tid  = threadIdx.x;
  int w    = tid >> 6;
  int lane = tid & 63;
  int q    = lane & 15;
  int kg   = lane >> 4;

  __shared__ __align__(16) float s_hi[64];
  __shared__ __align__(16) float s_pv[64];
  __shared__ __align__(16) float s_prior[NN];
  __shared__ __align__(16) float s_invn[NN];
  __shared__ __align__(16) float lrow[NN];
  __shared__ float red[8];

  float spsl  = softplusf(s_sl[0]);
  float spps  = softplusf(s_ps[0]);
  float spss  = softplusf(s_ss[0]);
  float invt  = 1.f / (softplusf(s_tp[0]) + 1e-4f);

  if (tid < 64){
    s_hi[tid] = hg  [(b*NN + i)*64 + tid];
    s_pv[tid] = pvec[(b*NN + i)*64 + tid];
  }
  {
    float4 ci0 = *(const float4*)(coords + i*NC);
    float4 ci1 = *(const float4*)(coords + i*NC + 4);
    for (int j = tid; j < NN; j += 256){
      float4 cj0 = *(const float4*)(coords + j*NC);
      float4 cj1 = *(const float4*)(coords + j*NC + 4);
      float dd = 0.f;
      dd = fmaf(ci0.x-cj0.x, ci0.x-cj0.x, dd);
      dd = fmaf(ci0.y-cj0.y, ci0.y-cj0.y, dd);
      dd = fmaf(ci0.z-cj0.z, ci0.z-cj0.z, dd);
      dd = fmaf(ci0.w-cj0.w, ci0.w-cj0.w, dd);
      dd = fmaf(ci1.x-cj1.x, ci1.x-cj1.x, dd);
      dd = fmaf(ci1.y-cj1.y, ci1.y-cj1.y, dd);
      dd = fmaf(ci1.z-cj1.z, ci1.z-cj1.z, dd);
      dd = fmaf(ci1.w-cj1.w, ci1.w-cj1.w, dd);
      float dist = sqrtf(fmaxf(dd, 1e-12f));
      s_prior[j] = (j == i) ? 0.f : spps / (1.f + dist);
      s_invn[j]  = invn[b*NN + j];
    }
  }
  __syncthreads();

  // B fragments: 24 x short8 (96 VGPRs)
  short8 bfr[6][4];
  #pragma unroll
  for (int ks = 0; ks < 6; ++ks)
    #pragma unroll
    for (int nt = 0; nt < 4; ++nt)
      bfr[ks][nt] = *(const short8*)(bfrag + ((ks*4 + nt)*64 + lane)*8);

  float hiA[16];
  {
    float4 t0 = *(const float4*)(s_hi + kg*8);
    float4 t1 = *(const float4*)(s_hi + kg*8 + 4);
    float4 t2 = *(const float4*)(s_hi + 32 + kg*8);
    float4 t3 = *(const float4*)(s_hi + 32 + kg*8 + 4);
    hiA[0]=t0.x; hiA[1]=t0.y; hiA[2]=t0.z; hiA[3]=t0.w;
    hiA[4]=t1.x; hiA[5]=t1.y; hiA[6]=t1.z; hiA[7]=t1.w;
    hiA[8]=t2.x; hiA[9]=t2.y; hiA[10]=t2.z; hiA[11]=t2.w;
    hiA[12]=t3.x; hiA[13]=t3.y; hiA[14]=t3.z; hiA[15]=t3.w;
  }
  float pv4[4], we2q[4];
  #pragma unroll
  for (int nt = 0; nt < 4; ++nt){
    pv4[nt]  = s_pv[nt*16 + q];
    we2q[nt] = We2[nt*16 + q];
  }
  float invni = invn[b*NN + i];
  float be2v  = be2[0];

  // preload first tile (f32 hj + bf16 hj fragments)
  float4 hj0, hj1, hj2, hj3; short8 hb0, hb1;
  {
    const float* hjp = hg + (size_t)(b*NN + w*16 + q)*64 + kg*8;
    hj0 = *(const float4*)(hjp);
    hj1 = *(const float4*)(hjp + 4);
    hj2 = *(const float4*)(hjp + 32);
    hj3 = *(const float4*)(hjp + 36);
    const short* hbp = hjbf + (size_t)(b*NN + w*16 + q)*64 + kg*8;
    hb0 = *(const short8*)(hbp);
    hb1 = *(const short8*)(hbp + 32);
  }

  for (int it = w; it < 32; it += 4){
    int jbase = it * 16;
    float4 nj0 = hj0, nj1 = hj1, nj2 = hj2, nj3 = hj3;
    short8 nb0 = hb0, nb1 = hb1;
    if (it + 4 < 32){
      const float* hjn = hg + (size_t)(b*NN + (it+4)*16 + q)*64 + kg*8;
      nj0 = *(const float4*)(hjn);
      nj1 = *(const float4*)(hjn + 4);
      nj2 = *(const float4*)(hjn + 32);
      nj3 = *(const float4*)(hjn + 36);
      const short* hbn = hjbf + (size_t)(b*NN + (it+4)*16 + q)*64 + kg*8;
      nb0 = *(const short8*)(hbn);
      nb1 = *(const short8*)(hbn + 32);
    }

    float hjA[16];
    hjA[0]=hj0.x; hjA[1]=hj0.y; hjA[2]=hj0.z; hjA[3]=hj0.w;
    hjA[4]=hj1.x; hjA[5]=hj1.y; hjA[6]=hj1.z; hjA[7]=hj1.w;
    hjA[8]=hj2.x; hjA[9]=hj2.y; hjA[10]=hj2.z; hjA[11]=hj2.w;
    hjA[12]=hj3.x; hjA[13]=hj3.y; hjA[14]=hj3.z; hjA[15]=hj3.w;

    // features: d = |hi-hj| (k 0..63), p = hi*hj (k 64..127), hj (k 128..191)
    uint4v ad0, ad1, ap0, ap1;
    float dotp = 0.f;
    #pragma unroll
    for (int w2 = 0; w2 < 4; ++w2){
      int e0 = 2*w2, e1 = 2*w2 + 1;
      float d00 = fabsf(hiA[e0]   - hjA[e0]);
      float d01 = fabsf(hiA[e1]   - hjA[e1]);
      float d10 = fabsf(hiA[8+e0] - hjA[8+e0]);
      float d11 = fabsf(hiA[8+e1] - hjA[8+e1]);
      float p00 = hiA[e0]   * hjA[e0];
      float p01 = hiA[e1]   * hjA[e1];
      float p10 = hiA[8+e0] * hjA[8+e0];
      float p11 = hiA[8+e1] * hjA[8+e1];
      dotp += (p00 + p01) + (p10 + p11);
      ad0[w2] = pk2(d00, d01);
      ad1[w2] = pk2(d10, d11);
      ap0[w2] = pk2(p00, p01);
      ap1[w2] = pk2(p10, p11);
    }
    short8 af0 = __builtin_bit_cast(short8, ad0);
    short8 af1 = __builtin_bit_cast(short8, ad1);
    short8 af2 = __builtin_bit_cast(short8, ap0);
    short8 af3 = __builtin_bit_cast(short8, ap1);

    f32x4 acc[4];
    #pragma unroll
    for (int nt = 0; nt < 4; ++nt)
      acc[nt] = (f32x4){pv4[nt], pv4[nt], pv4[nt], pv4[nt]};
    #pragma unroll
    for (int nt = 0; nt < 4; ++nt){
      acc[nt] = __builtin_amdgcn_mfma_f32_16x16x32_bf16(af0, bfr[0][nt], acc[nt], 0, 0, 0);
      acc[nt] = __builtin_amdgcn_mfma_f32_16x16x32_bf16(af1, bfr[1][nt], acc[nt], 0, 0, 0);
      acc[nt] = __builtin_amdgcn_mfma_f32_16x16x32_bf16(af2, bfr[2][nt], acc[nt], 0, 0, 0);
      acc[nt] = __builtin_amdgcn_mfma_f32_16x16x32_bf16(af3, bfr[3][nt], acc[nt], 0, 0, 0);
      acc[nt] = __builtin_amdgcn_mfma_f32_16x16x32_bf16(hb0, bfr[4][nt], acc[nt], 0, 0, 0);
      acc[nt] = __builtin_amdgcn_mfma_f32_16x16x32_bf16(hb1, bfr[5][nt], acc[nt], 0, 0, 0);
    }

    // epilogue: relu + We2 dot, reduce across 16 q-lanes
    float part[4] = {0.f, 0.f, 0.f, 0.f};
    #pragma unroll
    for (int nt = 0; nt < 4; ++nt)
      #pragma unroll
      for (int r = 0; r < 4; ++r)
        part[r] = fmaf(fmaxf(acc[nt][r], 0.f), we2q[nt], part[r]);
    #pragma unroll
    for (int m = 1; m < 16; m <<= 1){
      #pragma unroll
      for (int r = 0; r < 4; ++r) part[r] += __shfl_xor(part[r], m);
    }
    dotp += __shfl_xor(dotp, 16);
    dotp += __shfl_xor(dotp, 32);

    float4 pr4  = *(const float4*)(s_prior + jbase + kg*4);
    float4 inv4 = *(const float4*)(s_invn  + jbase + kg*4);
    float iv[4] = {inv4.x, inv4.y, inv4.z, inv4.w};
    float pr[4] = {pr4.x, pr4.y, pr4.z, pr4.w};
    float lg[4];
    #pragma unroll
    for (int r = 0; r < 4; ++r){
      int j2 = jbase + kg*4 + r;
      float dj   = __shfl(dotp, kg*4 + r);
      float cosv = dj * invni * iv[r];
      float ev   = part[r] + be2v + pr[r];
      lg[r] = (j2 == i) ? spsl : fmaf(spss, cosv, ev);
    }
    if (q == 0)
      *(float4*)(lrow + jbase + kg*4) = (float4){lg[0], lg[1], lg[2], lg[3]};

    hj0 = nj0; hj1 = nj1; hj2 = nj2; hj3 = nj3;
    hb0 = nb0; hb1 = nb1;
  }
  __syncthreads();

  // row softmax of lrow * invt
  float m1 = -INFINITY;
  for (int j = tid; j < NN; j += 256) m1 = fmaxf(m1, lrow[j]);
  #pragma unroll
  for (int msk = 1; msk < 64; msk <<= 1) m1 = fmaxf(m1, __shfl_xor(m1, msk));
  if (lane == 0) red[w] = m1;
  __syncthreads();
  m1 = fmaxf(fmaxf(red[0], red[1]), fmaxf(red[2], red[3]));

  float se = 0.f;
  for (int j = tid; j < NN; j += 256){
    float e = expf((lrow[j] - m1) * invt);
    lrow[j] = e;
    se += e;
  }
  #pragma unroll
  for (int msk = 1; msk < 64; msk <<= 1) se += __shfl_xor(se, msk);
  if (lane == 0) red[4 + w] = se;
  __syncthreads();
  se = red[4] + red[5] + red[6] + red[7];
  float inv_se = 1.f / se;

  float* urow = unsym + (size_t)(b*NN + i) * NN;
  for (int j = tid; j < NN; j += 256) urow[j] = lrow[j] * inv_se;
}

// ---------------- Kernel D: symmetrize + renormalize ----------------
__global__ __launch_bounds__(256) void k_sym(
    const float* __restrict__ u, float* __restrict__ out){
  int blk = blockIdx.x;
  int b = blk >> 9, i = blk & (NN-1);
  int tid = threadIdx.x;
  const float* urow = u + (size_t)(b*NN + i) * NN;
  float v0, v1, rs;
  {
    int j0 = tid, j1 = tid + 256;
    float a1 = urow[j0];
    float a2 = u[(size_t)(b*NN + j0) * NN + i];
    v0 = 0.5f*(a1 + a2);
    float a3 = urow[j1];
    float a4 = u[(size_t)(b*NN + j1) * NN + i];
    v1 = 0.5f*(a3 + a4);
    rs = v0 + v1;
  }
  int lane = tid & 63, w = tid >> 6;
  #pragma unroll
  for (int msk = 1; msk < 64; msk <<= 1) rs += __shfl_xor(rs, msk);
  __shared__ float red[4];
  if (lane == 0) red[w] = rs;
  __syncthreads();
  rs = red[0] + red[1] + red[2] + red[3];
  float inv = 1.f / fmaxf(rs, 1e-6f);
  float* orow = out + (size_t)(b*NN + i) * NN;
  orow[tid]       = v0 * inv;
  orow[tid + 256] = v1 * inv;
}

extern "C" void kernel_launch(void* const* d_in, const int* in_sizes, int n_in,
                              void* d_out, int out_size, void* d_ws, size_t ws_size,
                              hipStream_t stream){
  const float* x      = (const float*)d_in[0];
  const float* mask   = (const float*)d_in[1];
  const float* sctx   = (const float*)d_in[2];
  const float* coords = (const float*)d_in[3];
  const float* W1     = (const float*)d_in[4];
  const float* b1     = (const float*)d_in[5];
  const float* W2     = (const float*)d_in[6];
  const float* b2     = (const float*)d_in[7];
  const float* We1    = (const float*)d_in[8];
  const float* be1    = (const float*)d_in[9];
  const float* We2    = (const float*)d_in[10];
  const float* be2    = (const float*)d_in[11];
  const float* sl     = (const float*)d_in[12];
  const float* ps     = (const float*)d_in[13];
  const float* ss     = (const float*)d_in[14];
  const float* tp     = (const float*)d_in[15];

  float* ws     = (float*)d_ws;
  float* hgp    = ws + OFF_H;
  float* pvecp  = ws + OFF_PVEC;
  float* invnp  = ws + OFF_INVN;
  short* hjbfp  = (short*)(ws + OFF_HJBF);
  short* bfragp = (short*)(ws + OFF_BFRAG);
  float* unsym  = ws + OFF_UNSYM;
  float* out    = (float*)d_out;

  k_front<<<112, 256, 0, stream>>>(x, mask, sctx, W1, b1, W2, b2, We1, be1,
                                   hgp, pvecp, invnp, hjbfp, bfragp);
  k_pair <<<NB*NN, 256, 0, stream>>>(hgp, pvecp, invnp, hjbfp, bfragp, coords,
                                     We2, be2, sl, ps, ss, tp, unsym);
  k_sym  <<<NB*NN, 256, 0, stream>>>(unsym, out);
}

// Round 5
// 61.458 us; speedup vs baseline: 1.0572x; 1.0572x over previous
//
#include <hip/hip_runtime.h>
#include <hip/hip_bf16.h>
#include <math.h>

#define NB 2
#define NT 256
#define NN 512
#define NH 64
#define NS 8
#define NC 8

// workspace layout (float offsets)
#define OFF_H      0                          // 2*512*64 = 65536
#define OFF_PVEC   65536                      // 65536   (pre_i + be1)
#define OFF_INVN   (2*65536)                  // 1024
#define OFF_HJBF   (2*65536 + 1024)           // 65536 shorts = 32768 floats
#define OFF_BFRAG  (2*65536 + 1024 + 32768)   // 12288 shorts = 6144 floats
#define OFF_UNSYM  (OFF_BFRAG + 6144)         // 2*512*512 = 524288

typedef __attribute__((ext_vector_type(8))) short short8;
typedef __attribute__((ext_vector_type(4))) float f32x4;
typedef __attribute__((ext_vector_type(4))) unsigned uint4v;

__device__ __forceinline__ float softplusf(float x){
  if (x > 20.f) return x;
  return log1pf(expf(x));
}

__device__ __forceinline__ short f2bf(float x){
  __hip_bfloat16 h = __float2bfloat16(x);
  return __builtin_bit_cast(short, h);
}

__device__ __forceinline__ unsigned pk2(float a, float b){
  unsigned lo = (unsigned short)f2bf(a);
  unsigned hi = (unsigned short)f2bf(b);
  return lo | (hi << 16);
}

// ---------------- Kernel FRONT ----------------
// blocks 0..255: stats + node MLP for 4 nodes each (b = blk>>7, n0 = (blk&127)*4)
// blocks 256..303: bfrag prep (B-matrix -> bf16 MFMA fragments)
__global__ __launch_bounds__(256) void k_front(
    const float* __restrict__ x, const float* __restrict__ mask,
    const float* __restrict__ sctx,
    const float* __restrict__ W1, const float* __restrict__ b1,
    const float* __restrict__ W2, const float* __restrict__ b2,
    const float* __restrict__ We1, const float* __restrict__ be1,
    float* __restrict__ hg, float* __restrict__ pvec,
    float* __restrict__ invn, short* __restrict__ hjbf,
    short* __restrict__ bfrag){
  int blk = blockIdx.x;
  int tid = threadIdx.x;

  if (blk >= 256){
    // k<64: Wa = We1 rows 128..191 ; k<128: Wp = rows 192..255 ; k<192: Wj = rows 64..127
    int idx = (blk - 256)*256 + tid;         // 0..12287
    int e    = idx & 7;
    int lane = (idx >> 3) & 63;
    int frag = idx >> 9;                     // ks*4+nt
    int nt = frag & 3, ks = frag >> 2;
    int k = ks*32 + (lane >> 4)*8 + e;
    int n = nt*16 + (lane & 15);
    int row = (k < 64) ? (128 + k) : (k < 128) ? (192 + (k - 64)) : (64 + (k - 128));
    bfrag[idx] = f2bf(We1[row*NH + n]);
    return;
  }

  int b  = blk >> 7;
  int n0 = (blk & 127) * 4;

  // ---- phase 1: stats. 4 nl x 64 ts (4 t each) ----
  int nl = tid & 3;
  int ts = tid >> 2;                         // 0..63
  int n  = n0 + nl;

  float cnt = 0.f, sx = 0.f, sxx = 0.f;
  int lastt = 0;
  for (int t = ts*4; t < ts*4 + 4; ++t){
    int idx = (b*NT + t)*NN + n;
    float xv = x[idx];
    float mv = mask[idx];
    bool obs = (mv < 0.5f);
    if (obs){ cnt += 1.f; sx += xv; sxx += xv*xv; lastt = t; }
  }
  // wave-level reduce over the 16 ts-slices in this wave (lane bits 2..5)
  #pragma unroll
  for (int m = 4; m < 64; m <<= 1){
    cnt   += __shfl_xor(cnt,  m);
    sx    += __shfl_xor(sx,   m);
    sxx   += __shfl_xor(sxx,  m);
    lastt  = max(lastt, __shfl_xor(lastt, m));
  }
  int w = tid >> 6;
  __shared__ float r_cnt[4][4], r_sx[4][4], r_sxx[4][4];
  __shared__ int   r_lt[4][4];
  __shared__ float s_dyn[4][4];
  if ((tid & 63) < 4){                        // lanes 0..3 hold nl 0..3
    r_cnt[w][nl] = cnt; r_sx[w][nl] = sx; r_sxx[w][nl] = sxx; r_lt[w][nl] = lastt;
  }
  __syncthreads();
  if (tid < 4){
    float c = 0.f, s1 = 0.f, s2 = 0.f; int lt = 0;
    #pragma unroll
    for (int ww = 0; ww < 4; ++ww){
      c  += r_cnt[ww][tid]; s1 += r_sx[ww][tid]; s2 += r_sxx[ww][tid];
      lt  = max(lt, r_lt[ww][tid]);
    }
    float cc   = fmaxf(c, 1.f);
    float mean = s1 / cc;
    float var  = s2 / cc - mean*mean;
    float stdv = sqrtf(fmaxf(var, 0.f) + 1e-6f);
    float last = x[(b*NT + lt)*NN + n0 + tid];
    float mr   = 1.f - c * (1.f/(float)NT);
    s_dyn[tid][0] = mean; s_dyn[tid][1] = stdv; s_dyn[tid][2] = last; s_dyn[tid][3] = mr;
  }
  __syncthreads();

  // ---- phase 2: node MLP, wave w = node n0+w, lane c = channel ----
  int c = tid & 63;
  int gn = n0 + w;
  int bn = b*NN + gn;
  __shared__ float s_f[4][12];
  __shared__ float s_h1[4][64];
  __shared__ float s_h2[4][64];

  if (c < 4)       s_f[w][c] = s_dyn[w][c];
  else if (c < 12) s_f[w][c] = sctx[gn*NS + (c-4)];
  __syncthreads();

  float a = b1[c];
  #pragma unroll
  for (int k = 0; k < 12; ++k) a = fmaf(s_f[w][k], W1[k*NH + c], a);
  s_h1[w][c] = fmaxf(a, 0.f);
  __syncthreads();

  float a2 = b2[c];
  #pragma unroll 8
  for (int k = 0; k < 64; ++k) a2 = fmaf(s_h1[w][k], W2[k*NH + c], a2);
  a2 = fmaxf(a2, 0.f);

  float sq = a2*a2;
  #pragma unroll
  for (int m = 1; m < 64; m <<= 1) sq += __shfl_xor(sq, m);
  float inv = 1.f / fmaxf(sqrtf(sq), 1e-12f);

  s_h2[w][c] = a2;
  __syncthreads();

  float pi = be1[c];
  #pragma unroll 8
  for (int k = 0; k < 64; ++k) pi = fmaf(s_h2[w][k], We1[k*NH + c], pi);  // Wi rows 0..63

  hg  [bn*64 + c] = a2;
  pvec[bn*64 + c] = pi;
  hjbf[bn*64 + c] = f2bf(a2);
  if (c == 0) invn[bn] = inv;
}

// ---------------- Kernel C: MFMA pairwise edge MLP + logits + row softmax -----
// grid NB*NN (block per (b,i)), 256 thr = 4 waves; wave handles 16-j tiles
// it = w, w+4, ..., 28. MFMA 16x16x32 bf16: M=16 j, N=64 ch (4 n-tiles),
// K=192 ([|hi-hj|, hi*hj, hj]) = 6 k-steps. B-fragments staged in LDS.
__global__ __launch_bounds__(256) void k_pair(
    const float* __restrict__ hg, const float* __restrict__ pvec,
    const float* __restrict__ invn, const short* __restrict__ hjbf,
    const short* __restrict__ bfrag, const float* __restrict__ coords,
    const float* __restrict__ We2, const float* __restrict__ be2,
    const float* __restrict__ s_sl, const float* __restrict__ s_ps,
    const float* __restrict__ s_ss, const float* __restrict__ s_tp,
    float* __restrict__ unsym){
  int blk = blockIdx.x;
  int b = blk >> 9, i = blk & (NN-1);
  int tid  = threadIdx.x;
  int w    = tid >> 6;
  int lane = tid & 63;
  int q    = lane & 15;
  int kg   = lane >> 4;

  __shared__ __align__(16) short s_bf[12288];   // 24.5 KB B-fragments
  __shared__ __align__(16) float s_hi[64];
  __shared__ __align__(16) float s_pv[64];
  __shared__ __align__(16) float s_prior[NN];
  __shared__ __align__(16) float s_invn[NN];
  __shared__ __align__(16) float lrow[NN];
  __shared__ float red[8];

  float spsl  = softplusf(s_sl[0]);
  float spps  = softplusf(s_ps[0]);
  float spss  = softplusf(s_ss[0]);
  float invt  = 1.f / (softplusf(s_tp[0]) + 1e-4f);

  // stage B-fragments into LDS (1536 short8 chunks, 6 per thread)
  for (int cch = tid; cch < 1536; cch += 256)
    *(short8*)(s_bf + cch*8) = *(const short8*)(bfrag + cch*8);

  if (tid < 64){
    s_hi[tid] = hg  [(b*NN + i)*64 + tid];
    s_pv[tid] = pvec[(b*NN + i)*64 + tid];
  }
  {
    float4 ci0 = *(const float4*)(coords + i*NC);
    float4 ci1 = *(const float4*)(coords + i*NC + 4);
    for (int j = tid; j < NN; j += 256){
      float4 cj0 = *(const float4*)(coords + j*NC);
      float4 cj1 = *(const float4*)(coords + j*NC + 4);
      float dd = 0.f;
      dd = fmaf(ci0.x-cj0.x, ci0.x-cj0.x, dd);
      dd = fmaf(ci0.y-cj0.y, ci0.y-cj0.y, dd);
      dd = fmaf(ci0.z-cj0.z, ci0.z-cj0.z, dd);
      dd = fmaf(ci0.w-cj0.w, ci0.w-cj0.w, dd);
      dd = fmaf(ci1.x-cj1.x, ci1.x-cj1.x, dd);
      dd = fmaf(ci1.y-cj1.y, ci1.y-cj1.y, dd);
      dd = fmaf(ci1.z-cj1.z, ci1.z-cj1.z, dd);
      dd = fmaf(ci1.w-cj1.w, ci1.w-cj1.w, dd);
      float dist = sqrtf(fmaxf(dd, 1e-12f));
      s_prior[j] = (j == i) ? 0.f : spps / (1.f + dist);
      s_invn[j]  = invn[b*NN + j];
    }
  }
  __syncthreads();

  float hiA[16];
  {
    float4 t0 = *(const float4*)(s_hi + kg*8);
    float4 t1 = *(const float4*)(s_hi + kg*8 + 4);
    float4 t2 = *(const float4*)(s_hi + 32 + kg*8);
    float4 t3 = *(const float4*)(s_hi + 32 + kg*8 + 4);
    hiA[0]=t0.x; hiA[1]=t0.y; hiA[2]=t0.z; hiA[3]=t0.w;
    hiA[4]=t1.x; hiA[5]=t1.y; hiA[6]=t1.z; hiA[7]=t1.w;
    hiA[8]=t2.x; hiA[9]=t2.y; hiA[10]=t2.z; hiA[11]=t2.w;
    hiA[12]=t3.x; hiA[13]=t3.y; hiA[14]=t3.z; hiA[15]=t3.w;
  }
  float pv4[4], we2q[4];
  #pragma unroll
  for (int nt = 0; nt < 4; ++nt){
    pv4[nt]  = s_pv[nt*16 + q];
    we2q[nt] = We2[nt*16 + q];
  }
  float invni = invn[b*NN + i];
  float be2v  = be2[0];

  for (int it = w; it < 32; it += 4){
    int jbase = it * 16;
    // load hj tile (f32 for features/dot, bf16 for the Wj fragments)
    float4 hj0, hj1, hj2, hj3; short8 hb0, hb1;
    {
      const float* hjp = hg + (size_t)(b*NN + jbase + q)*64 + kg*8;
      hj0 = *(const float4*)(hjp);
      hj1 = *(const float4*)(hjp + 4);
      hj2 = *(const float4*)(hjp + 32);
      hj3 = *(const float4*)(hjp + 36);
      const short* hbp = hjbf + (size_t)(b*NN + jbase + q)*64 + kg*8;
      hb0 = *(const short8*)(hbp);
      hb1 = *(const short8*)(hbp + 32);
    }
    float hjA[16];
    hjA[0]=hj0.x; hjA[1]=hj0.y; hjA[2]=hj0.z; hjA[3]=hj0.w;
    hjA[4]=hj1.x; hjA[5]=hj1.y; hjA[6]=hj1.z; hjA[7]=hj1.w;
    hjA[8]=hj2.x; hjA[9]=hj2.y; hjA[10]=hj2.z; hjA[11]=hj2.w;
    hjA[12]=hj3.x; hjA[13]=hj3.y; hjA[14]=hj3.z; hjA[15]=hj3.w;

    // features: d = |hi-hj| (k 0..63), p = hi*hj (k 64..127), hj (k 128..191)
    uint4v ad0, ad1, ap0, ap1;
    float dotp = 0.f;
    #pragma unroll
    for (int w2 = 0; w2 < 4; ++w2){
      int e0 = 2*w2, e1 = 2*w2 + 1;
      float d00 = fabsf(hiA[e0]   - hjA[e0]);
      float d01 = fabsf(hiA[e1]   - hjA[e1]);
      float d10 = fabsf(hiA[8+e0] - hjA[8+e0]);
      float d11 = fabsf(hiA[8+e1] - hjA[8+e1]);
      float p00 = hiA[e0]   * hjA[e0];
      float p01 = hiA[e1]   * hjA[e1];
      float p10 = hiA[8+e0] * hjA[8+e0];
      float p11 = hiA[8+e1] * hjA[8+e1];
      dotp += (p00 + p01) + (p10 + p11);
      ad0[w2] = pk2(d00, d01);
      ad1[w2] = pk2(d10, d11);
      ap0[w2] = pk2(p00, p01);
      ap1[w2] = pk2(p10, p11);
    }
    short8 af0 = __builtin_bit_cast(short8, ad0);
    short8 af1 = __builtin_bit_cast(short8, ad1);
    short8 af2 = __builtin_bit_cast(short8, ap0);
    short8 af3 = __builtin_bit_cast(short8, ap1);

    f32x4 acc[4];
    #pragma unroll
    for (int nt = 0; nt < 4; ++nt)
      acc[nt] = (f32x4){pv4[nt], pv4[nt], pv4[nt], pv4[nt]};
    #pragma unroll
    for (int nt = 0; nt < 4; ++nt){
      const short* bp = s_bf + (size_t)nt*512 + (size_t)lane*8;
      short8 b0 = *(const short8*)(bp);
      short8 b1 = *(const short8*)(bp + 2048);
      short8 b2 = *(const short8*)(bp + 4096);
      short8 b3 = *(const short8*)(bp + 6144);
      short8 b4 = *(const short8*)(bp + 8192);
      short8 b5 = *(const short8*)(bp + 10240);
      acc[nt] = __builtin_amdgcn_mfma_f32_16x16x32_bf16(af0, b0, acc[nt], 0, 0, 0);
      acc[nt] = __builtin_amdgcn_mfma_f32_16x16x32_bf16(af1, b1, acc[nt], 0, 0, 0);
      acc[nt] = __builtin_amdgcn_mfma_f32_16x16x32_bf16(af2, b2, acc[nt], 0, 0, 0);
      acc[nt] = __builtin_amdgcn_mfma_f32_16x16x32_bf16(af3, b3, acc[nt], 0, 0, 0);
      acc[nt] = __builtin_amdgcn_mfma_f32_16x16x32_bf16(hb0, b4, acc[nt], 0, 0, 0);
      acc[nt] = __builtin_amdgcn_mfma_f32_16x16x32_bf16(hb1, b5, acc[nt], 0, 0, 0);
    }

    // epilogue: relu + We2 dot, reduce across 16 q-lanes
    float part[4] = {0.f, 0.f, 0.f, 0.f};
    #pragma unroll
    for (int nt = 0; nt < 4; ++nt)
      #pragma unroll
      for (int r = 0; r < 4; ++r)
        part[r] = fmaf(fmaxf(acc[nt][r], 0.f), we2q[nt], part[r]);
    #pragma unroll
    for (int m = 1; m < 16; m <<= 1){
      #pragma unroll
      for (int r = 0; r < 4; ++r) part[r] += __shfl_xor(part[r], m);
    }
    dotp += __shfl_xor(dotp, 16);
    dotp += __shfl_xor(dotp, 32);

    float4 pr4  = *(const float4*)(s_prior + jbase + kg*4);
    float4 inv4 = *(const float4*)(s_invn  + jbase + kg*4);
    float iv[4] = {inv4.x, inv4.y, inv4.z, inv4.w};
    float pr[4] = {pr4.x, pr4.y, pr4.z, pr4.w};
    float lg[4];
    #pragma unroll
    for (int r = 0; r < 4; ++r){
      int j2 = jbase + kg*4 + r;
      float dj   = __shfl(dotp, kg*4 + r);
      float cosv = dj * invni * iv[r];
      float ev   = part[r] + be2v + pr[r];
      lg[r] = (j2 == i) ? spsl : fmaf(spss, cosv, ev);
    }
    if (q == 0)
      *(float4*)(lrow + jbase + kg*4) = (float4){lg[0], lg[1], lg[2], lg[3]};
  }
  __syncthreads();

  // row softmax of lrow * invt
  float m1 = -INFINITY;
  for (int j = tid; j < NN; j += 256) m1 = fmaxf(m1, lrow[j]);
  #pragma unroll
  for (int msk = 1; msk < 64; msk <<= 1) m1 = fmaxf(m1, __shfl_xor(m1, msk));
  if (lane == 0) red[w] = m1;
  __syncthreads();
  m1 = fmaxf(fmaxf(red[0], red[1]), fmaxf(red[2], red[3]));

  float se = 0.f;
  for (int j = tid; j < NN; j += 256){
    float e = expf((lrow[j] - m1) * invt);
    lrow[j] = e;
    se += e;
  }
  #pragma unroll
  for (int msk = 1; msk < 64; msk <<= 1) se += __shfl_xor(se, msk);
  if (lane == 0) red[4 + w] = se;
  __syncthreads();
  se = red[4] + red[5] + red[6] + red[7];
  float inv_se = 1.f / se;

  float* urow = unsym + (size_t)(b*NN + i) * NN;
  for (int j = tid; j < NN; j += 256) urow[j] = lrow[j] * inv_se;
}

// ---------------- Kernel D: symmetrize + renormalize ----------------
__global__ __launch_bounds__(256) void k_sym(
    const float* __restrict__ u, float* __restrict__ out){
  int blk = blockIdx.x;
  int b = blk >> 9, i = blk & (NN-1);
  int tid = threadIdx.x;
  const float* urow = u + (size_t)(b*NN + i) * NN;
  float v0, v1, rs;
  {
    int j0 = tid, j1 = tid + 256;
    float a1 = urow[j0];
    float a2 = u[(size_t)(b*NN + j0) * NN + i];
    v0 = 0.5f*(a1 + a2);
    float a3 = urow[j1];
    float a4 = u[(size_t)(b*NN + j1) * NN + i];
    v1 = 0.5f*(a3 + a4);
    rs = v0 + v1;
  }
  int lane = tid & 63, w = tid >> 6;
  #pragma unroll
  for (int msk = 1; msk < 64; msk <<= 1) rs += __shfl_xor(rs, msk);
  __shared__ float red[4];
  if (lane == 0) red[w] = rs;
  __syncthreads();
  rs = red[0] + red[1] + red[2] + red[3];
  float inv = 1.f / fmaxf(rs, 1e-6f);
  float* orow = out + (size_t)(b*NN + i) * NN;
  orow[tid]       = v0 * inv;
  orow[tid + 256] = v1 * inv;
}

extern "C" void kernel_launch(void* const* d_in, const int* in_sizes, int n_in,
                              void* d_out, int out_size, void* d_ws, size_t ws_size,
                              hipStream_t stream){
  const float* x      = (const float*)d_in[0];
  const float* mask   = (const float*)d_in[1];
  const float* sctx   = (const float*)d_in[2];
  const float* coords = (const float*)d_in[3];
  const float* W1     = (const float*)d_in[4];
  const float* b1     = (const float*)d_in[5];
  const float* W2     = (const float*)d_in[6];
  const float* b2     = (const float*)d_in[7];
  const float* We1    = (const float*)d_in[8];
  const float* be1    = (const float*)d_in[9];
  const float* We2    = (const float*)d_in[10];
  const float* be2    = (const float*)d_in[11];
  const float* sl     = (const float*)d_in[12];
  const float* ps     = (const float*)d_in[13];
  const float* ss     = (const float*)d_in[14];
  const float* tp     = (const float*)d_in[15];

  float* ws     = (float*)d_ws;
  float* hgp    = ws + OFF_H;
  float* pvecp  = ws + OFF_PVEC;
  float* invnp  = ws + OFF_INVN;
  short* hjbfp  = (short*)(ws + OFF_HJBF);
  short* bfragp = (short*)(ws + OFF_BFRAG);
  float* unsym  = ws + OFF_UNSYM;
  float* out    = (float*)d_out;

  k_front<<<304, 256, 0, stream>>>(x, mask, sctx, W1, b1, W2, b2, We1, be1,
                                   hgp, pvecp, invnp, hjbfp, bfragp);
  k_pair <<<NB*NN, 256, 0, stream>>>(hgp, pvecp, invnp, hjbfp, bfragp, coords,
                                     We2, be2, sl, ps, ss, tp, unsym);
  k_sym  <<<NB*NN, 256, 0, stream>>>(unsym, out);
}

// Round 6
// 56.800 us; speedup vs baseline: 1.1438x; 1.0820x over previous
//
#include <hip/hip_runtime.h>
#include <hip/hip_bf16.h>
#include <math.h>

#define NB 2
#define NT 256
#define NN 512
#define NH 64
#define NS 8
#define NC 8

// workspace layout (float offsets)
#define OFF_H      0                          // 2*512*64 = 65536
#define OFF_PVEC   65536                      // 65536   (pre_i + be1)
#define OFF_INVN   (2*65536)                  // 1024
#define OFF_BFRAG  (2*65536 + 1024)           // 12288 shorts = 6144 floats
#define OFF_UNSYM  (OFF_BFRAG + 6144)         // 2*512*512 = 524288

typedef __attribute__((ext_vector_type(8))) short short8;
typedef __attribute__((ext_vector_type(4))) float f32x4;
typedef __attribute__((ext_vector_type(4))) unsigned uint4v;

__device__ __forceinline__ float softplusf(float x){
  if (x > 20.f) return x;
  return log1pf(expf(x));
}

__device__ __forceinline__ short f2bf(float x){
  __hip_bfloat16 h = __float2bfloat16(x);
  return __builtin_bit_cast(short, h);
}

__device__ __forceinline__ unsigned pk2(float a, float b){
  unsigned lo = (unsigned short)f2bf(a);
  unsigned hi = (unsigned short)f2bf(b);
  return lo | (hi << 16);
}

// DPP-based partial-sum step: x += x[lane via CTRL] (VALU only, no LDS pipe)
template<int CTRL>
__device__ __forceinline__ float dpp_addf(float x){
  int xi = __builtin_bit_cast(int, x);
  int yi = __builtin_amdgcn_update_dpp(0, xi, CTRL, 0xF, 0xF, true);
  return x + __builtin_bit_cast(float, yi);
}
// sum over the 16 lanes of a DPP row: xor1, xor2, ^7(half_mirror), ^15(mirror)
__device__ __forceinline__ float row16_sum(float x){
  x = dpp_addf<0xB1>(x);    // quad_perm [1,0,3,2]  : lane^1
  x = dpp_addf<0x4E>(x);    // quad_perm [2,3,0,1]  : lane^2
  x = dpp_addf<0x141>(x);   // row_half_mirror      : lane^7
  x = dpp_addf<0x140>(x);   // row_mirror           : lane^15
  return x;
}

// ---------------- Kernel FRONT ----------------
// blocks 0..255: stats + node MLP for 4 nodes each (b = blk>>7, n0 = (blk&127)*4)
// blocks 256..303: bfrag prep (B-matrix -> bf16 MFMA fragments)
__global__ __launch_bounds__(256) void k_front(
    const float* __restrict__ x, const float* __restrict__ mask,
    const float* __restrict__ sctx,
    const float* __restrict__ W1, const float* __restrict__ b1,
    const float* __restrict__ W2, const float* __restrict__ b2,
    const float* __restrict__ We1, const float* __restrict__ be1,
    float* __restrict__ hg, float* __restrict__ pvec,
    float* __restrict__ invn, short* __restrict__ bfrag){
  int blk = blockIdx.x;
  int tid = threadIdx.x;

  if (blk >= 256){
    // k<64: Wa = We1 rows 128..191 ; k<128: Wp = rows 192..255 ; k<192: Wj = rows 64..127
    int idx = (blk - 256)*256 + tid;         // 0..12287
    int e    = idx & 7;
    int lane = (idx >> 3) & 63;
    int frag = idx >> 9;                     // ks*4+nt
    int nt = frag & 3, ks = frag >> 2;
    int k = ks*32 + (lane >> 4)*8 + e;
    int n = nt*16 + (lane & 15);
    int row = (k < 64) ? (128 + k) : (k < 128) ? (192 + (k - 64)) : (64 + (k - 128));
    bfrag[idx] = f2bf(We1[row*NH + n]);
    return;
  }

  int b  = blk >> 7;
  int n0 = (blk & 127) * 4;

  // ---- phase 1: stats. 4 nl x 64 ts (4 t each) ----
  int nl = tid & 3;
  int ts = tid >> 2;                         // 0..63
  int n  = n0 + nl;

  float cnt = 0.f, sx = 0.f, sxx = 0.f;
  int lastt = 0;
  for (int t = ts*4; t < ts*4 + 4; ++t){
    int idx = (b*NT + t)*NN + n;
    float xv = x[idx];
    float mv = mask[idx];
    bool obs = (mv < 0.5f);
    if (obs){ cnt += 1.f; sx += xv; sxx += xv*xv; lastt = t; }
  }
  #pragma unroll
  for (int m = 4; m < 64; m <<= 1){
    cnt   += __shfl_xor(cnt,  m);
    sx    += __shfl_xor(sx,   m);
    sxx   += __shfl_xor(sxx,  m);
    lastt  = max(lastt, __shfl_xor(lastt, m));
  }
  int w = tid >> 6;
  __shared__ float r_cnt[4][4], r_sx[4][4], r_sxx[4][4];
  __shared__ int   r_lt[4][4];
  __shared__ float s_dyn[4][4];
  if ((tid & 63) < 4){
    r_cnt[w][nl] = cnt; r_sx[w][nl] = sx; r_sxx[w][nl] = sxx; r_lt[w][nl] = lastt;
  }
  __syncthreads();
  if (tid < 4){
    float c = 0.f, s1 = 0.f, s2 = 0.f; int lt = 0;
    #pragma unroll
    for (int ww = 0; ww < 4; ++ww){
      c  += r_cnt[ww][tid]; s1 += r_sx[ww][tid]; s2 += r_sxx[ww][tid];
      lt  = max(lt, r_lt[ww][tid]);
    }
    float cc   = fmaxf(c, 1.f);
    float mean = s1 / cc;
    float var  = s2 / cc - mean*mean;
    float stdv = sqrtf(fmaxf(var, 0.f) + 1e-6f);
    float last = x[(b*NT + lt)*NN + n0 + tid];
    float mr   = 1.f - c * (1.f/(float)NT);
    s_dyn[tid][0] = mean; s_dyn[tid][1] = stdv; s_dyn[tid][2] = last; s_dyn[tid][3] = mr;
  }
  __syncthreads();

  // ---- phase 2: node MLP, wave w = node n0+w, lane c = channel ----
  int c = tid & 63;
  int gn = n0 + w;
  int bn = b*NN + gn;
  __shared__ float s_f[4][12];
  __shared__ float s_h1[4][64];
  __shared__ float s_h2[4][64];

  if (c < 4)       s_f[w][c] = s_dyn[w][c];
  else if (c < 12) s_f[w][c] = sctx[gn*NS + (c-4)];
  __syncthreads();

  float a = b1[c];
  #pragma unroll
  for (int k = 0; k < 12; ++k) a = fmaf(s_f[w][k], W1[k*NH + c], a);
  s_h1[w][c] = fmaxf(a, 0.f);
  __syncthreads();

  float a2 = b2[c];
  #pragma unroll 8
  for (int k = 0; k < 64; ++k) a2 = fmaf(s_h1[w][k], W2[k*NH + c], a2);
  a2 = fmaxf(a2, 0.f);

  float sq = a2*a2;
  #pragma unroll
  for (int m = 1; m < 64; m <<= 1) sq += __shfl_xor(sq, m);
  float inv = 1.f / fmaxf(sqrtf(sq), 1e-12f);

  s_h2[w][c] = a2;
  __syncthreads();

  float pi = be1[c];
  #pragma unroll 8
  for (int k = 0; k < 64; ++k) pi = fmaf(s_h2[w][k], We1[k*NH + c], pi);  // Wi rows 0..63

  hg  [bn*64 + c] = a2;
  pvec[bn*64 + c] = pi;
  if (c == 0) invn[bn] = inv;
}

// ---------------- Kernel C: MFMA pairwise edge MLP + logits + row softmax -----
// grid NB*NN (block per (b,i)), 256 thr = 4 waves; wave handles 16-j tiles
// it = w, w+4, ..., 28. MFMA 16x16x32 bf16: M=16 j, N=64 ch (4 n-tiles),
// K=192 ([|hi-hj|, hi*hj, hj]) = 6 k-steps. B-fragments RESIDENT in registers
// (launch_bounds(256,2) -> 256-VGPR cap). Epilogue reduce via DPP (VALU-only).
__global__ __launch_bounds__(256, 2) void k_pair(
    const float* __restrict__ hg, const float* __restrict__ pvec,
    const float* __restrict__ invn,
    const short* __restrict__ bfrag, const float* __restrict__ coords,
    const float* __restrict__ We2, const float* __restrict__ be2,
    const float* __restrict__ s_sl, const float* __restrict__ s_ps,
    const float* __restrict__ s_ss, const float* __restrict__ s_tp,
    float* __restrict__ unsym){
  int blk = blockIdx.x;
  int b = blk >> 9, i = blk & (NN-1);
  int tid  = threadIdx.x;
  int w    = tid >> 6;
  int lane = tid & 63;
  int q    = lane & 15;
  int kg   = lane >> 4;

  __shared__ __align__(16) float s_hi[64];
  __shared__ __align__(16) float s_pv[64];
  __shared__ __align__(16) float s_prior[NN];
  __shared__ __align__(16) float s_invn[NN];
  __shared__ __align__(16) float lrow[NN];
  __shared__ float red[8];

  float spsl  = softplusf(s_sl[0]);
  float spps  = softplusf(s_ps[0]);
  float spss  = softplusf(s_ss[0]);
  float invt  = 1.f / (softplusf(s_tp[0]) + 1e-4f);

  if (tid < 64){
    s_hi[tid] = hg  [(b*NN + i)*64 + tid];
    s_pv[tid] = pvec[(b*NN + i)*64 + tid];
  }
  {
    float4 ci0 = *(const float4*)(coords + i*NC);
    float4 ci1 = *(const float4*)(coords + i*NC + 4);
    for (int j = tid; j < NN; j += 256){
      float4 cj0 = *(const float4*)(coords + j*NC);
      float4 cj1 = *(const float4*)(coords + j*NC + 4);
      float dd = 0.f;
      dd = fmaf(ci0.x-cj0.x, ci0.x-cj0.x, dd);
      dd = fmaf(ci0.y-cj0.y, ci0.y-cj0.y, dd);
      dd = fmaf(ci0.z-cj0.z, ci0.z-cj0.z, dd);
      dd = fmaf(ci0.w-cj0.w, ci0.w-cj0.w, dd);
      dd = fmaf(ci1.x-cj1.x, ci1.x-cj1.x, dd);
      dd = fmaf(ci1.y-cj1.y, ci1.y-cj1.y, dd);
      dd = fmaf(ci1.z-cj1.z, ci1.z-cj1.z, dd);
      dd = fmaf(ci1.w-cj1.w, ci1.w-cj1.w, dd);
      float dist = sqrtf(fmaxf(dd, 1e-12f));
      s_prior[j] = (j == i) ? 0.f : spps / (1.f + dist);
      s_invn[j]  = invn[b*NN + j];
    }
  }
  __syncthreads();

  // B fragments resident: 24 x short8 = 96 VGPRs, loaded once
  short8 bfr[6][4];
  #pragma unroll
  for (int ks = 0; ks < 6; ++ks)
    #pragma unroll
    for (int nt = 0; nt < 4; ++nt)
      bfr[ks][nt] = *(const short8*)(bfrag + ((ks*4 + nt)*64 + lane)*8);

  float hiA[16];
  {
    float4 t0 = *(const float4*)(s_hi + kg*8);
    float4 t1 = *(const float4*)(s_hi + kg*8 + 4);
    float4 t2 = *(const float4*)(s_hi + 32 + kg*8);
    float4 t3 = *(const float4*)(s_hi + 32 + kg*8 + 4);
    hiA[0]=t0.x; hiA[1]=t0.y; hiA[2]=t0.z; hiA[3]=t0.w;
    hiA[4]=t1.x; hiA[5]=t1.y; hiA[6]=t1.z; hiA[7]=t1.w;
    hiA[8]=t2.x; hiA[9]=t2.y; hiA[10]=t2.z; hiA[11]=t2.w;
    hiA[12]=t3.x; hiA[13]=t3.y; hiA[14]=t3.z; hiA[15]=t3.w;
  }
  float pv4[4], we2q[4];
  #pragma unroll
  for (int nt = 0; nt < 4; ++nt){
    pv4[nt]  = s_pv[nt*16 + q];
    we2q[nt] = We2[nt*16 + q];
  }
  float invni = invn[b*NN + i];
  float be2v  = be2[0];

  for (int it = w; it < 32; it += 4){
    int jbase = it * 16;
    // load hj tile (f32; bf16 A-frags rebuilt via pk2 -> identical rounding)
    float4 hj0, hj1, hj2, hj3;
    {
      const float* hjp = hg + (size_t)(b*NN + jbase + q)*64 + kg*8;
      hj0 = *(const float4*)(hjp);
      hj1 = *(const float4*)(hjp + 4);
      hj2 = *(const float4*)(hjp + 32);
      hj3 = *(const float4*)(hjp + 36);
    }
    float hjA[16];
    hjA[0]=hj0.x; hjA[1]=hj0.y; hjA[2]=hj0.z; hjA[3]=hj0.w;
    hjA[4]=hj1.x; hjA[5]=hj1.y; hjA[6]=hj1.z; hjA[7]=hj1.w;
    hjA[8]=hj2.x; hjA[9]=hj2.y; hjA[10]=hj2.z; hjA[11]=hj2.w;
    hjA[12]=hj3.x; hjA[13]=hj3.y; hjA[14]=hj3.z; hjA[15]=hj3.w;

    // features: d = |hi-hj| (k 0..63), p = hi*hj (k 64..127), hj (k 128..191)
    uint4v ad0, ad1, ap0, ap1, ah0, ah1;
    float dotp = 0.f;
    #pragma unroll
    for (int w2 = 0; w2 < 4; ++w2){
      int e0 = 2*w2, e1 = 2*w2 + 1;
      float d00 = fabsf(hiA[e0]   - hjA[e0]);
      float d01 = fabsf(hiA[e1]   - hjA[e1]);
      float d10 = fabsf(hiA[8+e0] - hjA[8+e0]);
      float d11 = fabsf(hiA[8+e1] - hjA[8+e1]);
      float p00 = hiA[e0]   * hjA[e0];
      float p01 = hiA[e1]   * hjA[e1];
      float p10 = hiA[8+e0] * hjA[8+e0];
      float p11 = hiA[8+e1] * hjA[8+e1];
      dotp += (p00 + p01) + (p10 + p11);
      ad0[w2] = pk2(d00, d01);
      ad1[w2] = pk2(d10, d11);
      ap0[w2] = pk2(p00, p01);
      ap1[w2] = pk2(p10, p11);
      ah0[w2] = pk2(hjA[e0],   hjA[e1]);
      ah1[w2] = pk2(hjA[8+e0], hjA[8+e1]);
    }
    short8 af0 = __builtin_bit_cast(short8, ad0);
    short8 af1 = __builtin_bit_cast(short8, ad1);
    short8 af2 = __builtin_bit_cast(short8, ap0);
    short8 af3 = __builtin_bit_cast(short8, ap1);
    short8 af4 = __builtin_bit_cast(short8, ah0);
    short8 af5 = __builtin_bit_cast(short8, ah1);

    f32x4 acc[4];
    #pragma unroll
    for (int nt = 0; nt < 4; ++nt)
      acc[nt] = (f32x4){pv4[nt], pv4[nt], pv4[nt], pv4[nt]};
    #pragma unroll
    for (int nt = 0; nt < 4; ++nt){
      acc[nt] = __builtin_amdgcn_mfma_f32_16x16x32_bf16(af0, bfr[0][nt], acc[nt], 0, 0, 0);
      acc[nt] = __builtin_amdgcn_mfma_f32_16x16x32_bf16(af1, bfr[1][nt], acc[nt], 0, 0, 0);
      acc[nt] = __builtin_amdgcn_mfma_f32_16x16x32_bf16(af2, bfr[2][nt], acc[nt], 0, 0, 0);
      acc[nt] = __builtin_amdgcn_mfma_f32_16x16x32_bf16(af3, bfr[3][nt], acc[nt], 0, 0, 0);
      acc[nt] = __builtin_amdgcn_mfma_f32_16x16x32_bf16(af4, bfr[4][nt], acc[nt], 0, 0, 0);
      acc[nt] = __builtin_amdgcn_mfma_f32_16x16x32_bf16(af5, bfr[5][nt], acc[nt], 0, 0, 0);
    }

    // epilogue: relu + We2 dot; reduce over the 16 q-lanes with DPP (VALU)
    float part[4] = {0.f, 0.f, 0.f, 0.f};
    #pragma unroll
    for (int nt = 0; nt < 4; ++nt)
      #pragma unroll
      for (int r = 0; r < 4; ++r)
        part[r] = fmaf(fmaxf(acc[nt][r], 0.f), we2q[nt], part[r]);
    #pragma unroll
    for (int r = 0; r < 4; ++r) part[r] = row16_sum(part[r]);

    // dot reduce across kg groups (lane ^16, ^32)
    dotp += __shfl_xor(dotp, 16);
    dotp += __shfl_xor(dotp, 32);

    float4 pr4  = *(const float4*)(s_prior + jbase + kg*4);
    float4 inv4 = *(const float4*)(s_invn  + jbase + kg*4);
    float iv[4] = {inv4.x, inv4.y, inv4.z, inv4.w};
    float pr[4] = {pr4.x, pr4.y, pr4.z, pr4.w};
    float lg[4];
    #pragma unroll
    for (int r = 0; r < 4; ++r){
      int j2 = jbase + kg*4 + r;
      float dj   = __shfl(dotp, kg*4 + r);
      float cosv = dj * invni * iv[r];
      float ev   = part[r] + be2v + pr[r];
      lg[r] = (j2 == i) ? spsl : fmaf(spss, cosv, ev);
    }
    if (q == 0)
      *(float4*)(lrow + jbase + kg*4) = (float4){lg[0], lg[1], lg[2], lg[3]};
  }
  __syncthreads();

  // row softmax of lrow * invt
  float m1 = -INFINITY;
  for (int j = tid; j < NN; j += 256) m1 = fmaxf(m1, lrow[j]);
  #pragma unroll
  for (int msk = 1; msk < 64; msk <<= 1) m1 = fmaxf(m1, __shfl_xor(m1, msk));
  if (lane == 0) red[w] = m1;
  __syncthreads();
  m1 = fmaxf(fmaxf(red[0], red[1]), fmaxf(red[2], red[3]));

  float se = 0.f;
  for (int j = tid; j < NN; j += 256){
    float e = expf((lrow[j] - m1) * invt);
    lrow[j] = e;
    se += e;
  }
  #pragma unroll
  for (int msk = 1; msk < 64; msk <<= 1) se += __shfl_xor(se, msk);
  if (lane == 0) red[4 + w] = se;
  __syncthreads();
  se = red[4] + red[5] + red[6] + red[7];
  float inv_se = 1.f / se;

  float* urow = unsym + (size_t)(b*NN + i) * NN;
  for (int j = tid; j < NN; j += 256) urow[j] = lrow[j] * inv_se;
}

// ---------------- Kernel D: symmetrize + renormalize ----------------
__global__ __launch_bounds__(256) void k_sym(
    const float* __restrict__ u, float* __restrict__ out){
  int blk = blockIdx.x;
  int b = blk >> 9, i = blk & (NN-1);
  int tid = threadIdx.x;
  const float* urow = u + (size_t)(b*NN + i) * NN;
  float v0, v1, rs;
  {
    int j0 = tid, j1 = tid + 256;
    float a1 = urow[j0];
    float a2 = u[(size_t)(b*NN + j0) * NN + i];
    v0 = 0.5f*(a1 + a2);
    float a3 = urow[j1];
    float a4 = u[(size_t)(b*NN + j1) * NN + i];
    v1 = 0.5f*(a3 + a4);
    rs = v0 + v1;
  }
  int lane = tid & 63, w = tid >> 6;
  #pragma unroll
  for (int msk = 1; msk < 64; msk <<= 1) rs += __shfl_xor(rs, msk);
  __shared__ float red[4];
  if (lane == 0) red[w] = rs;
  __syncthreads();
  rs = red[0] + red[1] + red[2] + red[3];
  float inv = 1.f / fmaxf(rs, 1e-6f);
  float* orow = out + (size_t)(b*NN + i) * NN;
  orow[tid]       = v0 * inv;
  orow[tid + 256] = v1 * inv;
}

extern "C" void kernel_launch(void* const* d_in, const int* in_sizes, int n_in,
                              void* d_out, int out_size, void* d_ws, size_t ws_size,
                              hipStream_t stream){
  const float* x      = (const float*)d_in[0];
  const float* mask   = (const float*)d_in[1];
  const float* sctx   = (const float*)d_in[2];
  const float* coords = (const float*)d_in[3];
  const float* W1     = (const float*)d_in[4];
  const float* b1     = (const float*)d_in[5];
  const float* W2     = (const float*)d_in[6];
  const float* b2     = (const float*)d_in[7];
  const float* We1    = (const float*)d_in[8];
  const float* be1    = (const float*)d_in[9];
  const float* We2    = (const float*)d_in[10];
  const float* be2    = (const float*)d_in[11];
  const float* sl     = (const float*)d_in[12];
  const float* ps     = (const float*)d_in[13];
  const float* ss     = (const float*)d_in[14];
  const float* tp     = (const float*)d_in[15];

  float* ws     = (float*)d_ws;
  float* hgp    = ws + OFF_H;
  float* pvecp  = ws + OFF_PVEC;
  float* invnp  = ws + OFF_INVN;
  short* bfragp = (short*)(ws + OFF_BFRAG);
  float* unsym  = ws + OFF_UNSYM;
  float* out    = (float*)d_out;

  k_front<<<304, 256, 0, stream>>>(x, mask, sctx, W1, b1, W2, b2, We1, be1,
                                   hgp, pvecp, invnp, bfragp);
  k_pair <<<NB*NN, 256, 0, stream>>>(hgp, pvecp, invnp, bfragp, coords,
                                     We2, be2, sl, ps, ss, tp, unsym);
  k_sym  <<<NB*NN, 256, 0, stream>>>(unsym, out);
}

// Round 7
// 55.885 us; speedup vs baseline: 1.1626x; 1.0164x over previous
//
#include <hip/hip_runtime.h>
#include <hip/hip_bf16.h>
#include <math.h>

#define NB 2
#define NT 256
#define NN 512
#define NH 64
#define NS 8
#define NC 8

// workspace layout (float offsets)
#define OFF_H      0                    // 2*512*64 = 65536
#define OFF_PVEC   65536                // 65536   (pre_i + be1)
#define OFF_INVN   131072               // 1024
#define OFF_WA     132096               // 4096 shorts = 2048 floats (Wa bf16 frags)
#define OFF_WJF    134144               // 4096 floats (Wj f32, frag order)
#define OFF_WPF    138240               // 4096 floats (Wp f32, frag order)
#define OFF_UNSYM  142336               // 2*512*512 = 524288

typedef __attribute__((ext_vector_type(8))) short short8;
typedef __attribute__((ext_vector_type(4))) float f32x4;
typedef __attribute__((ext_vector_type(4))) unsigned uint4v;

__device__ __forceinline__ float softplusf(float x){
  if (x > 20.f) return x;
  return log1pf(expf(x));
}

__device__ __forceinline__ short f2bf(float x){
  __hip_bfloat16 h = __float2bfloat16(x);
  return __builtin_bit_cast(short, h);
}

// single-instruction packed f32->bf16x2 (gfx950; no builtin -> inline asm)
__device__ __forceinline__ unsigned cvtpk(float a, float b){
  unsigned r;
  asm("v_cvt_pk_bf16_f32 %0, %1, %2" : "=v"(r) : "v"(a), "v"(b));
  return r;
}

// keep a 128-bit vector value opaque/resident (no rematerialization)
__device__ __forceinline__ void keep8(short8 &v){
  asm volatile("" : "+v"(v));
}

// DPP partial-sum: x += x[perm CTRL]
template<int CTRL>
__device__ __forceinline__ float dpp_addf(float x){
  int xi = __builtin_bit_cast(int, x);
  int yi = __builtin_amdgcn_update_dpp(0, xi, CTRL, 0xF, 0xF, true);
  return x + __builtin_bit_cast(float, yi);
}
__device__ __forceinline__ float row16_sum(float x){
  x = dpp_addf<0xB1>(x);    // lane^1
  x = dpp_addf<0x4E>(x);    // lane^2
  x = dpp_addf<0x141>(x);   // lane^7 (row_half_mirror)
  x = dpp_addf<0x140>(x);   // lane^15 (row_mirror)
  return x;
}

// ---------------- Kernel FRONT ----------------
// blocks 0..255: stats + node MLP (4 nodes each)
// blocks 256..303: weight prep: Wa bf16 frags, Wj/Wp f32 in frag order
__global__ __launch_bounds__(256) void k_front(
    const float* __restrict__ x, const float* __restrict__ mask,
    const float* __restrict__ sctx,
    const float* __restrict__ W1, const float* __restrict__ b1,
    const float* __restrict__ W2, const float* __restrict__ b2,
    const float* __restrict__ We1, const float* __restrict__ be1,
    float* __restrict__ hg, float* __restrict__ pvec,
    float* __restrict__ invn, short* __restrict__ wa_bf,
    float* __restrict__ wjf, float* __restrict__ wpf){
  int blk = blockIdx.x;
  int tid = threadIdx.x;

  if (blk >= 256){
    int pidx = (blk - 256)*256 + tid;        // 0..12287
    int e    = pidx & 7;
    int lane = (pidx >> 3) & 63;
    int frag = (pidx >> 9) & 7;              // ks*4+nt
    int nt = frag & 3, ks = frag >> 2;
    int kg = lane >> 4, q = lane & 15;
    int kk = ks*32 + kg*8 + e;               // 0..63
    int c  = nt*16 + q;
    if (pidx < 4096){
      wa_bf[pidx] = f2bf(We1[(128 + kk)*NH + c]);          // Wa rows 128..191
    } else if (pidx < 8192){
      wjf[pidx - 4096] = We1[(64 + kk)*NH + c];            // Wj rows 64..127
    } else {
      wpf[pidx - 8192] = We1[(192 + kk)*NH + c];           // Wp rows 192..255
    }
    return;
  }

  int b  = blk >> 7;
  int n0 = (blk & 127) * 4;

  // ---- phase 1: stats. 4 nl x 64 ts (4 t each) ----
  int nl = tid & 3;
  int ts = tid >> 2;
  int n  = n0 + nl;

  float cnt = 0.f, sx = 0.f, sxx = 0.f;
  int lastt = 0;
  for (int t = ts*4; t < ts*4 + 4; ++t){
    int idx = (b*NT + t)*NN + n;
    float xv = x[idx];
    float mv = mask[idx];
    bool obs = (mv < 0.5f);
    if (obs){ cnt += 1.f; sx += xv; sxx += xv*xv; lastt = t; }
  }
  #pragma unroll
  for (int m = 4; m < 64; m <<= 1){
    cnt   += __shfl_xor(cnt,  m);
    sx    += __shfl_xor(sx,   m);
    sxx   += __shfl_xor(sxx,  m);
    lastt  = max(lastt, __shfl_xor(lastt, m));
  }
  int w = tid >> 6;
  __shared__ float r_cnt[4][4], r_sx[4][4], r_sxx[4][4];
  __shared__ int   r_lt[4][4];
  __shared__ float s_dyn[4][4];
  if ((tid & 63) < 4){
    r_cnt[w][nl] = cnt; r_sx[w][nl] = sx; r_sxx[w][nl] = sxx; r_lt[w][nl] = lastt;
  }
  __syncthreads();
  if (tid < 4){
    float c = 0.f, s1 = 0.f, s2 = 0.f; int lt = 0;
    #pragma unroll
    for (int ww = 0; ww < 4; ++ww){
      c  += r_cnt[ww][tid]; s1 += r_sx[ww][tid]; s2 += r_sxx[ww][tid];
      lt  = max(lt, r_lt[ww][tid]);
    }
    float cc   = fmaxf(c, 1.f);
    float mean = s1 / cc;
    float var  = s2 / cc - mean*mean;
    float stdv = sqrtf(fmaxf(var, 0.f) + 1e-6f);
    float last = x[(b*NT + lt)*NN + n0 + tid];
    float mr   = 1.f - c * (1.f/(float)NT);
    s_dyn[tid][0] = mean; s_dyn[tid][1] = stdv; s_dyn[tid][2] = last; s_dyn[tid][3] = mr;
  }
  __syncthreads();

  // ---- phase 2: node MLP, wave w = node n0+w, lane c = channel ----
  int c = tid & 63;
  int gn = n0 + w;
  int bn = b*NN + gn;
  __shared__ float s_f[4][12];
  __shared__ float s_h1[4][64];
  __shared__ float s_h2[4][64];

  if (c < 4)       s_f[w][c] = s_dyn[w][c];
  else if (c < 12) s_f[w][c] = sctx[gn*NS + (c-4)];
  __syncthreads();

  float a = b1[c];
  #pragma unroll
  for (int k = 0; k < 12; ++k) a = fmaf(s_f[w][k], W1[k*NH + c], a);
  s_h1[w][c] = fmaxf(a, 0.f);
  __syncthreads();

  float a2 = b2[c];
  #pragma unroll 8
  for (int k = 0; k < 64; ++k) a2 = fmaf(s_h1[w][k], W2[k*NH + c], a2);
  a2 = fmaxf(a2, 0.f);

  float sq = a2*a2;
  #pragma unroll
  for (int m = 1; m < 64; m <<= 1) sq += __shfl_xor(sq, m);
  float inv = 1.f / fmaxf(sqrtf(sq), 1e-12f);

  s_h2[w][c] = a2;
  __syncthreads();

  float pi = be1[c];
  #pragma unroll 8
  for (int k = 0; k < 64; ++k) pi = fmaf(s_h2[w][k], We1[k*NH + c], pi);  // Wi rows 0..63

  hg  [bn*64 + c] = a2;
  pvec[bn*64 + c] = pi;
  if (c == 0) invn[bn] = inv;
}

// ---------------- Kernel C: pairwise edge MLP (K=128) + logits + softmax -----
// grid NB*NN, 256 thr = 4 waves; wave handles tiles it = w, w+4, ..., 28.
// hidden = relu(pv_i + [|hi-hj| ; hj] @ [Wa ; Wj + diag(hi)Wp]); 16 MFMA/iter.
__global__ __launch_bounds__(256, 2) void k_pair(
    const float* __restrict__ hg, const float* __restrict__ pvec,
    const float* __restrict__ invn,
    const short* __restrict__ wa_bf, const float* __restrict__ wjf,
    const float* __restrict__ wpf, const float* __restrict__ coords,
    const float* __restrict__ We2, const float* __restrict__ be2,
    const float* __restrict__ s_sl, const float* __restrict__ s_ps,
    const float* __restrict__ s_ss, const float* __restrict__ s_tp,
    float* __restrict__ unsym){
  int blk = blockIdx.x;
  int b = blk >> 9, i = blk & (NN-1);
  int tid  = threadIdx.x;
  int w    = tid >> 6;
  int lane = tid & 63;
  int q    = lane & 15;
  int kg   = lane >> 4;

  __shared__ __align__(16) float s_hi[64];
  __shared__ __align__(16) float s_pv[64];
  __shared__ __align__(16) float s_prior[NN];
  __shared__ __align__(16) float s_invn[NN];
  __shared__ __align__(16) float lrow[NN];
  __shared__ float red[8];

  float spsl  = softplusf(s_sl[0]);
  float spps  = softplusf(s_ps[0]);
  float spss  = softplusf(s_ss[0]);
  float invt  = 1.f / (softplusf(s_tp[0]) + 1e-4f);

  if (tid < 64){
    s_hi[tid] = hg  [(b*NN + i)*64 + tid];
    s_pv[tid] = pvec[(b*NN + i)*64 + tid];
  }
  {
    float4 ci0 = *(const float4*)(coords + i*NC);
    float4 ci1 = *(const float4*)(coords + i*NC + 4);
    for (int j = tid; j < NN; j += 256){
      float4 cj0 = *(const float4*)(coords + j*NC);
      float4 cj1 = *(const float4*)(coords + j*NC + 4);
      float dd = 0.f;
      dd = fmaf(ci0.x-cj0.x, ci0.x-cj0.x, dd);
      dd = fmaf(ci0.y-cj0.y, ci0.y-cj0.y, dd);
      dd = fmaf(ci0.z-cj0.z, ci0.z-cj0.z, dd);
      dd = fmaf(ci0.w-cj0.w, ci0.w-cj0.w, dd);
      dd = fmaf(ci1.x-cj1.x, ci1.x-cj1.x, dd);
      dd = fmaf(ci1.y-cj1.y, ci1.y-cj1.y, dd);
      dd = fmaf(ci1.z-cj1.z, ci1.z-cj1.z, dd);
      dd = fmaf(ci1.w-cj1.w, ci1.w-cj1.w, dd);
      float dist = sqrtf(fmaxf(dd, 1e-12f));
      s_prior[j] = (j == i) ? 0.f : spps / (1.f + dist);
      s_invn[j]  = invn[b*NN + j];
    }
  }
  __syncthreads();

  // per-lane hi slice (same k-mapping as A fragments)
  float hiA[16];
  {
    float4 t0 = *(const float4*)(s_hi + kg*8);
    float4 t1 = *(const float4*)(s_hi + kg*8 + 4);
    float4 t2 = *(const float4*)(s_hi + 32 + kg*8);
    float4 t3 = *(const float4*)(s_hi + 32 + kg*8 + 4);
    hiA[0]=t0.x; hiA[1]=t0.y; hiA[2]=t0.z; hiA[3]=t0.w;
    hiA[4]=t1.x; hiA[5]=t1.y; hiA[6]=t1.z; hiA[7]=t1.w;
    hiA[8]=t2.x; hiA[9]=t2.y; hiA[10]=t2.z; hiA[11]=t2.w;
    hiA[12]=t3.x; hiA[13]=t3.y; hiA[14]=t3.z; hiA[15]=t3.w;
  }

  // Wa fragments (8), pinned resident
  short8 wa[2][4];
  #pragma unroll
  for (int ks = 0; ks < 2; ++ks)
    #pragma unroll
    for (int nt = 0; nt < 4; ++nt){
      wa[ks][nt] = *(const short8*)(wa_bf + ((ks*4 + nt)*64 + lane)*8);
      keep8(wa[ks][nt]);
    }

  // combined fragments cw = bf16(Wj + hi*Wp) (8) — computed, inherently resident
  short8 cw[2][4];
  #pragma unroll
  for (int ks2 = 0; ks2 < 2; ++ks2)
    #pragma unroll
    for (int nt = 0; nt < 4; ++nt){
      const float* wj = wjf + ((ks2*4 + nt)*64 + lane)*8;
      const float* wp = wpf + ((ks2*4 + nt)*64 + lane)*8;
      float4 j0 = *(const float4*)(wj);
      float4 j1 = *(const float4*)(wj + 4);
      float4 p0 = *(const float4*)(wp);
      float4 p1 = *(const float4*)(wp + 4);
      int hb = ks2*8;
      uint4v u;
      u[0] = cvtpk(fmaf(hiA[hb+0], p0.x, j0.x), fmaf(hiA[hb+1], p0.y, j0.y));
      u[1] = cvtpk(fmaf(hiA[hb+2], p0.z, j0.z), fmaf(hiA[hb+3], p0.w, j0.w));
      u[2] = cvtpk(fmaf(hiA[hb+4], p1.x, j1.x), fmaf(hiA[hb+5], p1.y, j1.y));
      u[3] = cvtpk(fmaf(hiA[hb+6], p1.z, j1.z), fmaf(hiA[hb+7], p1.w, j1.w));
      cw[ks2][nt] = __builtin_bit_cast(short8, u);
    }

  float pv4[4], we2q[4];
  #pragma unroll
  for (int nt = 0; nt < 4; ++nt){
    pv4[nt]  = s_pv[nt*16 + q];
    we2q[nt] = We2[nt*16 + q];
  }
  float invni = invn[b*NN + i];
  float be2v  = be2[0];
  int   srcl  = (lane & 48) | (((lane >> 4) & 3) << 2) | (lane & 3);

  for (int it = w; it < 32; it += 4){
    int jbase = it * 16;
    float4 hj0, hj1, hj2, hj3;
    {
      const float* hjp = hg + (size_t)(b*NN + jbase + q)*64 + kg*8;
      hj0 = *(const float4*)(hjp);
      hj1 = *(const float4*)(hjp + 4);
      hj2 = *(const float4*)(hjp + 32);
      hj3 = *(const float4*)(hjp + 36);
    }
    float hjA[16];
    hjA[0]=hj0.x; hjA[1]=hj0.y; hjA[2]=hj0.z; hjA[3]=hj0.w;
    hjA[4]=hj1.x; hjA[5]=hj1.y; hjA[6]=hj1.z; hjA[7]=hj1.w;
    hjA[8]=hj2.x; hjA[9]=hj2.y; hjA[10]=hj2.z; hjA[11]=hj2.w;
    hjA[12]=hj3.x; hjA[13]=hj3.y; hjA[14]=hj3.z; hjA[15]=hj3.w;

    // features: |hi-hj| (k 0..63) and hj (k 64..127); f32 dot on the side
    uint4v u0, u1, u2, u3;
    float dotp = 0.f;
    #pragma unroll
    for (int w2 = 0; w2 < 4; ++w2){
      int e0 = 2*w2, e1 = 2*w2 + 1;
      u0[w2] = cvtpk(fabsf(hiA[e0]   - hjA[e0]),  fabsf(hiA[e1]   - hjA[e1]));
      u1[w2] = cvtpk(fabsf(hiA[8+e0] - hjA[8+e0]), fabsf(hiA[8+e1] - hjA[8+e1]));
      u2[w2] = cvtpk(hjA[e0],   hjA[e1]);
      u3[w2] = cvtpk(hjA[8+e0], hjA[8+e1]);
      dotp = fmaf(hiA[e0],   hjA[e0],   dotp);
      dotp = fmaf(hiA[e1],   hjA[e1],   dotp);
      dotp = fmaf(hiA[8+e0], hjA[8+e0], dotp);
      dotp = fmaf(hiA[8+e1], hjA[8+e1], dotp);
    }
    short8 af0 = __builtin_bit_cast(short8, u0);
    short8 af1 = __builtin_bit_cast(short8, u1);
    short8 af2 = __builtin_bit_cast(short8, u2);
    short8 af3 = __builtin_bit_cast(short8, u3);

    f32x4 acc[4];
    #pragma unroll
    for (int nt = 0; nt < 4; ++nt)
      acc[nt] = (f32x4){pv4[nt], pv4[nt], pv4[nt], pv4[nt]};
    #pragma unroll
    for (int nt = 0; nt < 4; ++nt){
      acc[nt] = __builtin_amdgcn_mfma_f32_16x16x32_bf16(af0, wa[0][nt], acc[nt], 0, 0, 0);
      acc[nt] = __builtin_amdgcn_mfma_f32_16x16x32_bf16(af1, wa[1][nt], acc[nt], 0, 0, 0);
      acc[nt] = __builtin_amdgcn_mfma_f32_16x16x32_bf16(af2, cw[0][nt], acc[nt], 0, 0, 0);
      acc[nt] = __builtin_amdgcn_mfma_f32_16x16x32_bf16(af3, cw[1][nt], acc[nt], 0, 0, 0);
    }

    // epilogue: relu + We2 dot; DPP row-sum; 3 cross-lane ops total
    float part[4] = {0.f, 0.f, 0.f, 0.f};
    #pragma unroll
    for (int nt = 0; nt < 4; ++nt)
      #pragma unroll
      for (int r = 0; r < 4; ++r)
        part[r] = fmaf(fmaxf(acc[nt][r], 0.f), we2q[nt], part[r]);
    #pragma unroll
    for (int r = 0; r < 4; ++r) part[r] = row16_sum(part[r]);

    dotp += __shfl_xor(dotp, 16);
    dotp += __shfl_xor(dotp, 32);
    float dj = __shfl(dotp, srcl);       // dot for j = jbase + kg*4 + (lane&3)

    if (q < 4){
      int j2 = jbase + kg*4 + q;
      float ps = part[0];
      ps = (q == 1) ? part[1] : ps;
      ps = (q == 2) ? part[2] : ps;
      ps = (q == 3) ? part[3] : ps;
      float cosv = dj * invni * s_invn[j2];
      float ev   = ps + be2v + s_prior[j2];
      lrow[j2] = (j2 == i) ? spsl : fmaf(spss, cosv, ev);
    }
  }
  __syncthreads();

  // row softmax of lrow * invt
  float m1 = -INFINITY;
  for (int j = tid; j < NN; j += 256) m1 = fmaxf(m1, lrow[j]);
  #pragma unroll
  for (int msk = 1; msk < 64; msk <<= 1) m1 = fmaxf(m1, __shfl_xor(m1, msk));
  if (lane == 0) red[w] = m1;
  __syncthreads();
  m1 = fmaxf(fmaxf(red[0], red[1]), fmaxf(red[2], red[3]));

  float se = 0.f;
  for (int j = tid; j < NN; j += 256){
    float e = expf((lrow[j] - m1) * invt);
    lrow[j] = e;
    se += e;
  }
  #pragma unroll
  for (int msk = 1; msk < 64; msk <<= 1) se += __shfl_xor(se, msk);
  if (lane == 0) red[4 + w] = se;
  __syncthreads();
  se = red[4] + red[5] + red[6] + red[7];
  float inv_se = 1.f / se;

  float* urow = unsym + (size_t)(b*NN + i) * NN;
  for (int j = tid; j < NN; j += 256) urow[j] = lrow[j] * inv_se;
}

// ---------------- Kernel D: symmetrize + renormalize ----------------
__global__ __launch_bounds__(256) void k_sym(
    const float* __restrict__ u, float* __restrict__ out){
  int blk = blockIdx.x;
  int b = blk >> 9, i = blk & (NN-1);
  int tid = threadIdx.x;
  const float* urow = u + (size_t)(b*NN + i) * NN;
  float v0, v1, rs;
  {
    int j0 = tid, j1 = tid + 256;
    float a1 = urow[j0];
    float a2 = u[(size_t)(b*NN + j0) * NN + i];
    v0 = 0.5f*(a1 + a2);
    float a3 = urow[j1];
    float a4 = u[(size_t)(b*NN + j1) * NN + i];
    v1 = 0.5f*(a3 + a4);
    rs = v0 + v1;
  }
  int lane = tid & 63, w = tid >> 6;
  #pragma unroll
  for (int msk = 1; msk < 64; msk <<= 1) rs += __shfl_xor(rs, msk);
  __shared__ float red[4];
  if (lane == 0) red[w] = rs;
  __syncthreads();
  rs = red[0] + red[1] + red[2] + red[3];
  float inv = 1.f / fmaxf(rs, 1e-6f);
  float* orow = out + (size_t)(b*NN + i) * NN;
  orow[tid]       = v0 * inv;
  orow[tid + 256] = v1 * inv;
}

extern "C" void kernel_launch(void* const* d_in, const int* in_sizes, int n_in,
                              void* d_out, int out_size, void* d_ws, size_t ws_size,
                              hipStream_t stream){
  const float* x      = (const float*)d_in[0];
  const float* mask   = (const float*)d_in[1];
  const float* sctx   = (const float*)d_in[2];
  const float* coords = (const float*)d_in[3];
  const float* W1     = (const float*)d_in[4];
  const float* b1     = (const float*)d_in[5];
  const float* W2     = (const float*)d_in[6];
  const float* b2     = (const float*)d_in[7];
  const float* We1    = (const float*)d_in[8];
  const float* be1    = (const float*)d_in[9];
  const float* We2    = (const float*)d_in[10];
  const float* be2    = (const float*)d_in[11];
  const float* sl     = (const float*)d_in[12];
  const float* ps     = (const float*)d_in[13];
  const float* ss     = (const float*)d_in[14];
  const float* tp     = (const float*)d_in[15];

  float* ws     = (float*)d_ws;
  float* hgp    = ws + OFF_H;
  float* pvecp  = ws + OFF_PVEC;
  float* invnp  = ws + OFF_INVN;
  short* wabfp  = (short*)(ws + OFF_WA);
  float* wjfp   = ws + OFF_WJF;
  float* wpfp   = ws + OFF_WPF;
  float* unsym  = ws + OFF_UNSYM;
  float* out    = (float*)d_out;

  k_front<<<304, 256, 0, stream>>>(x, mask, sctx, W1, b1, W2, b2, We1, be1,
                                   hgp, pvecp, invnp, wabfp, wjfp, wpfp);
  k_pair <<<NB*NN, 256, 0, stream>>>(hgp, pvecp, invnp, wabfp, wjfp, wpfp,
                                     coords, We2, be2, sl, ps, ss, tp, unsym);
  k_sym  <<<NB*NN, 256, 0, stream>>>(unsym, out);
}